// Round 1
// baseline (8527.317 us; speedup 1.0000x reference)
//
#include <hip/hip_runtime.h>
#include <math.h>

#ifndef M_PI
#define M_PI 3.14159265358979323846
#endif

struct Filt { float f[12]; };

// ---------------------------------------------------------------------------
// Host-side kaiser-sinc filter (matches reference kaiser_sinc_filter1d for
// cutoff=0.25, half_width=0.3, ks=12; FILT_UP == FILT_DOWN).
// ---------------------------------------------------------------------------
static double bessel_i0(double x) {
  double sum = 1.0, term = 1.0;
  for (int k = 1; k < 64; ++k) {
    term *= x / (2.0 * k);
    double t2 = term * term;
    sum += t2;
    if (t2 < 1e-22 * sum) break;
  }
  return sum;
}

static void compute_filter(float* out12) {
  const int ks = 12;
  const double cutoff = 0.25, half_width = 0.3;
  const int half_size = 6;
  double delta_f = 4.0 * half_width;
  double A = 2.285 * (half_size - 1) * M_PI * delta_f + 7.95;
  double beta;
  if (A > 50.0)       beta = 0.1102 * (A - 8.7);
  else if (A >= 21.0) beta = 0.5842 * pow(A - 21.0, 0.4) + 0.07886 * (A - 21.0);
  else                beta = 0.0;
  double i0b = bessel_i0(beta);
  double f[12], s = 0.0;
  for (int n = 0; n < ks; ++n) {
    double ratio = (n - (ks - 1) / 2.0) / ((ks - 1) / 2.0);
    double arg = 1.0 - ratio * ratio;
    double wnd = bessel_i0(beta * sqrt(arg > 0.0 ? arg : 0.0)) / i0b;
    double time = (n - half_size) + 0.5;
    double xx = 2.0 * cutoff * time;
    double sinc = (xx == 0.0) ? 1.0 : sin(M_PI * xx) / (M_PI * xx);
    f[n] = 2.0 * cutoff * wnd * sinc;
    s += f[n];
  }
  for (int n = 0; n < ks; ++n) out12[n] = (float)(f[n] / s);
}

// ---------------------------------------------------------------------------
// Fused alias-free activation: upsample(x2, edge-pad) -> snake_beta ->
// downsample(/2, edge-pad). Derivation (verified vs jax conv semantics):
//   up[2q]   = 2*sum_s F[2s]  *x[clamp(q-3+s)]     s=0..5
//   up[2q+1] = 2*sum_s F[2s+1]*x[clamp(q-2+s)]
//   sb[p]    = up[p] + (1/(e^beta+eps)) * sin(e^alpha*up[p])^2
//   down[t]  = sum_u F[u]*sb[clamp(2t+u-5, 0, 2T-1)]   u=0..11
// Optional residual add (last stage).
// ---------------------------------------------------------------------------
#define ATILE 256
#define XS_N (ATILE + 10)     // x[t0-5 .. t0+ATILE+4]
#define SB_N (2 * ATILE + 10) // sb[2*t0-5 .. 2*t0+2*ATILE+4]

__global__ __launch_bounds__(256) void act_kernel(
    const float* __restrict__ in, float* __restrict__ out,
    const float* __restrict__ alpha_log, const float* __restrict__ beta_log,
    const float* __restrict__ resid, int C, int T, Filt fl)
{
  __shared__ float xs[XS_N];
  __shared__ float sb[SB_N];
  const int c = blockIdx.y, b = blockIdx.z;
  const int t0 = blockIdx.x * ATILE;
  const long row = ((long)(b * C + c)) * T;
  const float a  = __expf(alpha_log[c]);
  const float rb = 1.0f / (__expf(beta_log[c]) + 1e-9f);
  const int tid = threadIdx.x;

  // Stage x tile (edge-clamped)
  for (int i = tid; i < XS_N; i += 256) {
    int gx = t0 - 5 + i;
    gx = min(max(gx, 0), T - 1);
    xs[i] = in[row + gx];
  }
  __syncthreads();

  // Upsample + snake into LDS
  const int P0 = 2 * t0 - 5;
  for (int idx = tid; idx < SB_N; idx += 256) {
    int p = P0 + idx;
    float up;
    if (p & 1) {
      int q = (p - 1) >> 1;           // works for negative p too
      int base = q - t0 + 3;          // xs index of x[q-2]
      up = fl.f[1] * xs[base]     + fl.f[3] * xs[base + 1] + fl.f[5]  * xs[base + 2]
         + fl.f[7] * xs[base + 3] + fl.f[9] * xs[base + 4] + fl.f[11] * xs[base + 5];
    } else {
      int q = p >> 1;
      int base = q - t0 + 2;          // xs index of x[q-3]
      up = fl.f[0] * xs[base]     + fl.f[2] * xs[base + 1] + fl.f[4]  * xs[base + 2]
         + fl.f[6] * xs[base + 3] + fl.f[8] * xs[base + 4] + fl.f[10] * xs[base + 5];
    }
    up *= 2.0f;
    float s = __sinf(a * up);
    sb[idx] = up + rb * s * s;
  }
  __syncthreads();

  // Downsample (+ optional residual)
  const int t = t0 + tid;
  float acc = 0.0f;
#pragma unroll
  for (int u = 0; u < 12; ++u) {
    int p = 2 * t + u - 5;
    p = min(max(p, 0), 2 * T - 1);
    acc += fl.f[u] * sb[p - P0];
  }
  if (resid) acc += resid[row + t];
  out[row + t] = acc;
}

// ---------------------------------------------------------------------------
// conv1d: out[b,co,t] = bias[co] + sum_{ci,d} w[co,ci,d] * in[b,ci,t-1+d]
// (zero padding). LDS-tiled: 64co x 64t per block, 4x4 register microtile,
// ci staged in chunks of 16. fp32 (no fp32 MFMA on CDNA4 — vector ALU).
// ---------------------------------------------------------------------------
#define CO_TILE 64
#define T_TILE 64
#define CK 16

__global__ __launch_bounds__(256) void conv_kernel(
    const float* __restrict__ in, const float* __restrict__ w,
    const float* __restrict__ bias, float* __restrict__ out, int C, int T)
{
  __shared__ float wl[CK * 3][CO_TILE + 1];  // [ci*3+d][co], +1 pad kills write conflicts
  __shared__ float xl[CK][T_TILE + 2];       // [ci][t0-1 .. t0+64]
  const int t0  = blockIdx.x * T_TILE;
  const int co0 = blockIdx.y * CO_TILE;
  const int b   = blockIdx.z;
  const int tid = threadIdx.x;
  const int tx = tid & 15;                   // t groups of 4
  const int ty = tid >> 4;                   // co groups of 4
  const int tbase  = t0 + tx * 4;
  const int cobase = co0 + ty * 4;

  float acc[4][4];
#pragma unroll
  for (int i = 0; i < 4; ++i) {
    float bv = bias[cobase + i];
#pragma unroll
    for (int j = 0; j < 4; ++j) acc[i][j] = bv;
  }

  for (int ci0 = 0; ci0 < C; ci0 += CK) {
    __syncthreads();
    // stage weights: for fixed co, (ci0..ci0+15, d) is 48 contiguous floats
    for (int i = tid; i < CO_TILE * CK * 3; i += 256) {
      int col = i / (CK * 3);
      int j   = i - col * (CK * 3);          // = cil*3 + d
      wl[j][col] = w[((long)(co0 + col) * C + ci0) * 3 + j];
    }
    // stage input tile (zero-padded at row ends)
    for (int i = tid; i < CK * (T_TILE + 2); i += 256) {
      int cil = i / (T_TILE + 2);
      int tt  = i - cil * (T_TILE + 2);
      int gt  = t0 - 1 + tt;
      float v = 0.0f;
      if (gt >= 0 && gt < T) v = in[((long)(b * C + ci0 + cil)) * T + gt];
      xl[cil][tt] = v;
    }
    __syncthreads();

#pragma unroll
    for (int cil = 0; cil < CK; ++cil) {
      float xv[6];
#pragma unroll
      for (int j = 0; j < 6; ++j) xv[j] = xl[cil][tx * 4 + j];
      float wv[3][4];
#pragma unroll
      for (int d = 0; d < 3; ++d)
#pragma unroll
        for (int i = 0; i < 4; ++i) wv[d][i] = wl[cil * 3 + d][ty * 4 + i];
#pragma unroll
      for (int i = 0; i < 4; ++i)
#pragma unroll
        for (int j = 0; j < 4; ++j)
          acc[i][j] += wv[0][i] * xv[j] + wv[1][i] * xv[j + 1] + wv[2][i] * xv[j + 2];
    }
  }

#pragma unroll
  for (int i = 0; i < 4; ++i) {
    long orow = ((long)(b * C + cobase + i)) * T;
#pragma unroll
    for (int j = 0; j < 4; ++j) out[orow + tbase + j] = acc[i][j];
  }
}

// ---------------------------------------------------------------------------
// Launch: act1(x->out) -> conv1(out->ws) -> act2(ws->out) -> conv2(out->ws)
//         -> act3(ws->out, +x residual). Only one 134MB scratch buffer.
// ---------------------------------------------------------------------------
extern "C" void kernel_launch(void* const* d_in, const int* in_sizes, int n_in,
                              void* d_out, int out_size, void* d_ws, size_t ws_size,
                              hipStream_t stream) {
  const float* x      = (const float*)d_in[0];
  const float* w1     = (const float*)d_in[1];
  const float* b1     = (const float*)d_in[2];
  const float* w2     = (const float*)d_in[3];
  const float* b2     = (const float*)d_in[4];
  const float* alpha1 = (const float*)d_in[5];
  const float* beta1  = (const float*)d_in[6];
  const float* alpha2 = (const float*)d_in[7];
  const float* beta2  = (const float*)d_in[8];
  float* out = (float*)d_out;

  const int C = in_sizes[2];                 // 512 (from b1)
  const long total = (long)in_sizes[0];      // B*C*T
  const int T = 8192;
  const int B = (int)(total / ((long)C * T));

  float* bufA = (float*)d_ws;                // B*C*T floats scratch

  Filt fl;
  compute_filter(fl.f);

  dim3 actGrid(T / ATILE, C, B);
  dim3 convGrid(T / T_TILE, C / CO_TILE, B);

  act_kernel<<<actGrid, 256, 0, stream>>>(x, out, alpha1, beta1, nullptr, C, T, fl);
  conv_kernel<<<convGrid, 256, 0, stream>>>(out, w1, b1, bufA, C, T);
  act_kernel<<<actGrid, 256, 0, stream>>>(bufA, out, alpha1, beta1, nullptr, C, T, fl);
  conv_kernel<<<convGrid, 256, 0, stream>>>(out, w2, b2, bufA, C, T);
  act_kernel<<<actGrid, 256, 0, stream>>>(bufA, out, alpha2, beta2, x, C, T, fl);
}

// Round 2
// 1252.956 us; speedup vs baseline: 6.8058x; 6.8058x over previous
//
#include <hip/hip_runtime.h>
#include <hip/hip_bf16.h>
#include <math.h>

#ifndef M_PI
#define M_PI 3.14159265358979323846
#endif

typedef __attribute__((ext_vector_type(8))) short bf16x8;
typedef __attribute__((ext_vector_type(4))) short bf16x4;
typedef __attribute__((ext_vector_type(4))) float f32x4;

struct Filt { float f[12]; };

// ---------------------------------------------------------------------------
// Host-side kaiser-sinc filter (matches reference; FILT_UP == FILT_DOWN).
// ---------------------------------------------------------------------------
static double bessel_i0(double x) {
  double sum = 1.0, term = 1.0;
  for (int k = 1; k < 64; ++k) {
    term *= x / (2.0 * k);
    double t2 = term * term;
    sum += t2;
    if (t2 < 1e-22 * sum) break;
  }
  return sum;
}

static void compute_filter(float* out12) {
  const int ks = 12;
  const double cutoff = 0.25, half_width = 0.3;
  const int half_size = 6;
  double delta_f = 4.0 * half_width;
  double A = 2.285 * (half_size - 1) * M_PI * delta_f + 7.95;
  double beta;
  if (A > 50.0)       beta = 0.1102 * (A - 8.7);
  else if (A >= 21.0) beta = 0.5842 * pow(A - 21.0, 0.4) + 0.07886 * (A - 21.0);
  else                beta = 0.0;
  double i0b = bessel_i0(beta);
  double f[12], s = 0.0;
  for (int n = 0; n < ks; ++n) {
    double ratio = (n - (ks - 1) / 2.0) / ((ks - 1) / 2.0);
    double arg = 1.0 - ratio * ratio;
    double wnd = bessel_i0(beta * sqrt(arg > 0.0 ? arg : 0.0)) / i0b;
    double time = (n - half_size) + 0.5;
    double xx = 2.0 * cutoff * time;
    double sinc = (xx == 0.0) ? 1.0 : sin(M_PI * xx) / (M_PI * xx);
    f[n] = 2.0 * cutoff * wnd * sinc;
    s += f[n];
  }
  for (int n = 0; n < ks; ++n) out12[n] = (float)(f[n] / s);
}

__device__ __forceinline__ ushort f2bf(float f) {
  __hip_bfloat16 h = __float2bfloat16(f);
  return *(ushort*)&h;
}

// ---------------------------------------------------------------------------
// act_t: fused upsample->snake->downsample, input [B][C][T] (fp32 or bf16),
// output TRANSPOSED [B][T][C] bf16 (B-operand layout for the MFMA conv).
// Tile: 64c x 64t per block.
//   up[2q]   = 2*sum_s F[2s]  *x[clamp(q-3+s)]
//   up[2q+1] = 2*sum_s F[2s+1]*x[clamp(q-2+s)]
//   sb[p]    = up[p] + rb*sin(a*up[p])^2
//   down[t]  = sum_u F[u]*sb[clamp(2t+u-5)]
// ---------------------------------------------------------------------------
template <typename TIN>
__global__ __launch_bounds__(256) void act_t(
    const TIN* __restrict__ in, __hip_bfloat16* __restrict__ out,
    const float* __restrict__ alpha_log, const float* __restrict__ beta_log,
    int C, int T, Filt fl)
{
  __shared__ float xs[64 * 80];   // xs[c][j], x[clamp(t0-5+j)], j<80 (reused as ys)
  __shared__ float sb[64 * 139];  // sb[c][pp], pp=0..137 (stride 139: odd, no conflicts)
  const int t0 = blockIdx.x * 64;
  const int c0 = blockIdx.y * 64;
  const int b  = blockIdx.z;
  const int tid = threadIdx.x;

  for (int i = tid; i < 64 * 80; i += 256) {
    int c = i / 80, j = i - c * 80;
    int t = min(max(t0 - 5 + j, 0), T - 1);
    xs[i] = (float)in[((long)(b * C + c0 + c)) * T + t];
  }
  __syncthreads();

  for (int i = tid; i < 64 * 138; i += 256) {
    int c = i / 138, pp = i - c * 138;
    int p = 2 * t0 - 5 + pp;
    const float* xr = xs + c * 80;   // xr[j] = x[t0-5+j]
    float up;
    if (p & 1) {
      int q = (p - 1) >> 1;
      int base = q - t0 + 3;         // index of x[q-2]
      up = fl.f[1] * xr[base]     + fl.f[3] * xr[base + 1] + fl.f[5]  * xr[base + 2]
         + fl.f[7] * xr[base + 3] + fl.f[9] * xr[base + 4] + fl.f[11] * xr[base + 5];
    } else {
      int q = p >> 1;
      int base = q - t0 + 2;         // index of x[q-3]
      up = fl.f[0] * xr[base]     + fl.f[2] * xr[base + 1] + fl.f[4]  * xr[base + 2]
         + fl.f[6] * xr[base + 3] + fl.f[8] * xr[base + 4] + fl.f[10] * xr[base + 5];
    }
    up *= 2.0f;
    float a  = __expf(alpha_log[c0 + c]);
    float rb = 1.0f / (__expf(beta_log[c0 + c]) + 1e-9f);
    float s = __sinf(a * up);
    sb[c * 139 + pp] = up + rb * s * s;
  }
  __syncthreads();

  float* ys = xs;  // xs dead after sb phase; ys[tl][c], 64*64 <= 64*80
  {
    int c = tid & 63, tg = tid >> 6;
#pragma unroll
    for (int k = 0; k < 16; ++k) {
      int tl = tg * 16 + k;
      int t = t0 + tl;
      float acc = 0.0f;
#pragma unroll
      for (int u = 0; u < 12; ++u) {
        int p = 2 * t + u - 5;
        p = min(max(p, 0), 2 * T - 1);
        acc += fl.f[u] * sb[c * 139 + (p - (2 * t0 - 5))];
      }
      ys[tl * 64 + c] = acc;
    }
  }
  __syncthreads();

  for (int i = tid; i < 64 * 64; i += 256) {
    int tl = i >> 6, c = i & 63;
    out[((long)b * T + t0 + tl) * C + c0 + c] = __float2bfloat16(ys[i]);
  }
}

// ---------------------------------------------------------------------------
// act_n (final stage): input [B][C][T] bf16, output [B][C][T] fp32 + residual.
// Round-1 streaming structure (verified correct).
// ---------------------------------------------------------------------------
#define ATILE 256
#define XS_N (ATILE + 10)
#define SB_N (2 * ATILE + 10)

__global__ __launch_bounds__(256) void act_n(
    const __hip_bfloat16* __restrict__ in, float* __restrict__ out,
    const float* __restrict__ alpha_log, const float* __restrict__ beta_log,
    const float* __restrict__ resid, int C, int T, Filt fl)
{
  __shared__ float xs[XS_N];
  __shared__ float sb[SB_N];
  const int c = blockIdx.y, b = blockIdx.z;
  const int t0 = blockIdx.x * ATILE;
  const long row = ((long)(b * C + c)) * T;
  const float a  = __expf(alpha_log[c]);
  const float rb = 1.0f / (__expf(beta_log[c]) + 1e-9f);
  const int tid = threadIdx.x;

  for (int i = tid; i < XS_N; i += 256) {
    int gx = t0 - 5 + i;
    gx = min(max(gx, 0), T - 1);
    xs[i] = (float)in[row + gx];
  }
  __syncthreads();

  const int P0 = 2 * t0 - 5;
  for (int idx = tid; idx < SB_N; idx += 256) {
    int p = P0 + idx;
    float up;
    if (p & 1) {
      int q = (p - 1) >> 1;
      int base = q - t0 + 3;
      up = fl.f[1] * xs[base]     + fl.f[3] * xs[base + 1] + fl.f[5]  * xs[base + 2]
         + fl.f[7] * xs[base + 3] + fl.f[9] * xs[base + 4] + fl.f[11] * xs[base + 5];
    } else {
      int q = p >> 1;
      int base = q - t0 + 2;
      up = fl.f[0] * xs[base]     + fl.f[2] * xs[base + 1] + fl.f[4]  * xs[base + 2]
         + fl.f[6] * xs[base + 3] + fl.f[8] * xs[base + 4] + fl.f[10] * xs[base + 5];
    }
    up *= 2.0f;
    float s = __sinf(a * up);
    sb[idx] = up + rb * s * s;
  }
  __syncthreads();

  const int t = t0 + tid;
  float acc = 0.0f;
#pragma unroll
  for (int u = 0; u < 12; ++u) {
    int p = 2 * t + u - 5;
    p = min(max(p, 0), 2 * T - 1);
    acc += fl.f[u] * sb[p - P0];
  }
  acc += resid[row + t];
  out[row + t] = acc;
}

// ---------------------------------------------------------------------------
// conv_mfma: out[b,co,t] = bias[co] + sum_{ci,d} w[co,ci,d]*in[b,ci,t-1+d]
// (zero pad). Implicit GEMM, mfma_f32_16x16x32_bf16, tap-decomposed:
// 3 accumulating GEMMs with t-shifted B reads from one LDS tile.
//   A[m][k]: m=lane&15, k=quad*8+j  (weights, [d][co][ci] in LDS)
//   B[k][n]: n=lane&15, k=quad*8+j  (input, transposed [t][ci] in LDS)
//   D[m][n]: n=lane&15, m=quad*4+reg
// Block: 64co x 256t, BK=32 ci/step, 4 waves each owning a 64t slice.
// Unpadded 64B LDS rows == m97's empirically-fine bank pattern.
// Weights converted fp32->bf16 during staging (vectorized: source layout
// [co][ci][d] gives 12 contiguous floats = 4ci x 3d -> three short4 stores).
// ---------------------------------------------------------------------------
#define MT 64
#define NTC 256
#define BK 32

__global__ __launch_bounds__(256) void conv_mfma(
    const __hip_bfloat16* __restrict__ inT,  // [B][T][C]
    const float* __restrict__ w,             // [C][C][3]
    const float* __restrict__ bias,          // [C]
    __hip_bfloat16* __restrict__ out,        // [B][C][T]
    int C, int T)
{
  __shared__ ushort wl[3][MT][BK];       // [d][co][ci]
  __shared__ ushort xs[NTC + 2][BK];     // [t - (t0-1)][ci]
  const int t0  = blockIdx.x * NTC;
  const int co0 = blockIdx.y * MT;
  const int b   = blockIdx.z;
  const int tid  = threadIdx.x;
  const int lane = tid & 63;
  const int wave = tid >> 6;
  const int ln15 = lane & 15;
  const int quad = lane >> 4;

  f32x4 acc[4][4];
#pragma unroll
  for (int mi = 0; mi < 4; ++mi)
#pragma unroll
    for (int ni = 0; ni < 4; ++ni) acc[mi][ni] = (f32x4){0.f, 0.f, 0.f, 0.f};

  const long inbase = (long)b * T * C;

  for (int ci0 = 0; ci0 < C; ci0 += BK) {
    __syncthreads();
    // --- stage weights: 64co x (32ci x 3d) fp32 -> bf16 LDS, all vectorized
    for (int g = tid; g < MT * 8; g += 256) {
      int co = g >> 3, cch = g & 7;   // cch: 4-ci chunk
      const float* src = w + ((long)(co0 + co) * C + ci0) * 3 + cch * 12;
      f32x4 f0 = *(const f32x4*)(src);
      f32x4 f1 = *(const f32x4*)(src + 4);
      f32x4 f2 = *(const f32x4*)(src + 8);
      float fv[12] = {f0.x, f0.y, f0.z, f0.w, f1.x, f1.y, f1.z, f1.w,
                      f2.x, f2.y, f2.z, f2.w};
#pragma unroll
      for (int d = 0; d < 3; ++d) {
        bf16x4 sv = {(short)f2bf(fv[d]), (short)f2bf(fv[3 + d]),
                     (short)f2bf(fv[6 + d]), (short)f2bf(fv[9 + d])};
        *(bf16x4*)&wl[d][co][cch * 4] = sv;
      }
    }
    // --- stage input: rows t0-1 .. t0+NTC, 32 ci each (64B, zero-padded t)
    for (int i = tid; i < (NTC + 2) * 4; i += 256) {
      int tl = i >> 2, seg = i & 3;
      int t = t0 - 1 + tl;
      uint4 v = {0u, 0u, 0u, 0u};
      if (t >= 0 && t < T)
        v = *(const uint4*)((const ushort*)inT + inbase + (long)t * C + ci0 + seg * 8);
      *(uint4*)&xs[tl][seg * 8] = v;
    }
    __syncthreads();

#pragma unroll
    for (int d = 0; d < 3; ++d) {
      bf16x8 afr[4], bfr[4];
#pragma unroll
      for (int mi = 0; mi < 4; ++mi)
        afr[mi] = *(const bf16x8*)&wl[d][mi * 16 + ln15][quad * 8];
#pragma unroll
      for (int ni = 0; ni < 4; ++ni)
        bfr[ni] = *(const bf16x8*)&xs[wave * 64 + ni * 16 + ln15 + d][quad * 8];
#pragma unroll
      for (int mi = 0; mi < 4; ++mi)
#pragma unroll
        for (int ni = 0; ni < 4; ++ni)
          acc[mi][ni] = __builtin_amdgcn_mfma_f32_16x16x32_bf16(
              afr[mi], bfr[ni], acc[mi][ni], 0, 0, 0);
    }
  }

  // --- epilogue: D[m][n]: n(t)=lane&15, m(co)=quad*4+reg
#pragma unroll
  for (int mi = 0; mi < 4; ++mi) {
#pragma unroll
    for (int r = 0; r < 4; ++r) {
      int co = co0 + mi * 16 + quad * 4 + r;
      float bv = bias[co];
      long orow = ((long)(b * C + co)) * T;
#pragma unroll
      for (int ni = 0; ni < 4; ++ni) {
        int t = t0 + wave * 64 + ni * 16 + ln15;
        out[orow + t] = __float2bfloat16(acc[mi][ni][r] + bv);
      }
    }
  }
}

// ---------------------------------------------------------------------------
// Pipeline: act1(x -> ws0 [t][c]) -> conv1(ws0 -> ws1 [co][t]) ->
//           act2(ws1 -> ws0 [t][c]) -> conv2(ws0 -> ws1) ->
//           act3(ws1 + x -> out fp32). ws = 2 x 67MB bf16 halves = 134MB.
// ---------------------------------------------------------------------------
extern "C" void kernel_launch(void* const* d_in, const int* in_sizes, int n_in,
                              void* d_out, int out_size, void* d_ws, size_t ws_size,
                              hipStream_t stream) {
  const float* x      = (const float*)d_in[0];
  const float* w1     = (const float*)d_in[1];
  const float* b1     = (const float*)d_in[2];
  const float* w2     = (const float*)d_in[3];
  const float* b2     = (const float*)d_in[4];
  const float* alpha1 = (const float*)d_in[5];
  const float* beta1  = (const float*)d_in[6];
  const float* alpha2 = (const float*)d_in[7];
  const float* beta2  = (const float*)d_in[8];
  float* out = (float*)d_out;

  const int C = in_sizes[2];             // 512
  const long total = (long)in_sizes[0];  // B*C*T
  const int T = 8192;
  const int B = (int)(total / ((long)C * T));

  __hip_bfloat16* ws0 = (__hip_bfloat16*)d_ws;           // [B][T][C]
  __hip_bfloat16* ws1 = ws0 + (size_t)B * C * T;         // [B][C][T]

  Filt fl;
  compute_filter(fl.f);

  dim3 actTGrid(T / 64, C / 64, B);
  dim3 convGrid(T / NTC, C / MT, B);
  dim3 actNGrid(T / ATILE, C, B);

  act_t<float><<<actTGrid, 256, 0, stream>>>(x, ws0, alpha1, beta1, C, T, fl);
  conv_mfma<<<convGrid, 256, 0, stream>>>(ws0, w1, b1, ws1, C, T);
  act_t<__hip_bfloat16><<<actTGrid, 256, 0, stream>>>(ws1, ws0, alpha1, beta1, C, T, fl);
  conv_mfma<<<convGrid, 256, 0, stream>>>(ws0, w2, b2, ws1, C, T);
  act_n<<<actNGrid, 256, 0, stream>>>(ws1, out, alpha2, beta2, x, C, T, fl);
}

// Round 3
// 1062.499 us; speedup vs baseline: 8.0257x; 1.1793x over previous
//
#include <hip/hip_runtime.h>
#include <hip/hip_bf16.h>
#include <math.h>

#ifndef M_PI
#define M_PI 3.14159265358979323846
#endif

typedef __attribute__((ext_vector_type(8))) short bf16x8;
typedef __attribute__((ext_vector_type(4))) float f32x4;

struct Filt { float f[12]; };

// ---------------------------------------------------------------------------
// Host-side kaiser-sinc filter (matches reference; FILT_UP == FILT_DOWN).
// ---------------------------------------------------------------------------
static double bessel_i0(double x) {
  double sum = 1.0, term = 1.0;
  for (int k = 1; k < 64; ++k) {
    term *= x / (2.0 * k);
    double t2 = term * term;
    sum += t2;
    if (t2 < 1e-22 * sum) break;
  }
  return sum;
}

static void compute_filter(float* out12) {
  const int ks = 12;
  const double cutoff = 0.25, half_width = 0.3;
  const int half_size = 6;
  double delta_f = 4.0 * half_width;
  double A = 2.285 * (half_size - 1) * M_PI * delta_f + 7.95;
  double beta;
  if (A > 50.0)       beta = 0.1102 * (A - 8.7);
  else if (A >= 21.0) beta = 0.5842 * pow(A - 21.0, 0.4) + 0.07886 * (A - 21.0);
  else                beta = 0.0;
  double i0b = bessel_i0(beta);
  double f[12], s = 0.0;
  for (int n = 0; n < ks; ++n) {
    double ratio = (n - (ks - 1) / 2.0) / ((ks - 1) / 2.0);
    double arg = 1.0 - ratio * ratio;
    double wnd = bessel_i0(beta * sqrt(arg > 0.0 ? arg : 0.0)) / i0b;
    double time = (n - half_size) + 0.5;
    double xx = 2.0 * cutoff * time;
    double sinc = (xx == 0.0) ? 1.0 : sin(M_PI * xx) / (M_PI * xx);
    f[n] = 2.0 * cutoff * wnd * sinc;
    s += f[n];
  }
  for (int n = 0; n < ks; ++n) out12[n] = (float)(f[n] / s);
}

__device__ __forceinline__ ushort f2bf(float f) {
  __hip_bfloat16 h = __float2bfloat16(f);
  return *(ushort*)&h;
}

__device__ __forceinline__ void gl_lds16(const void* g, void* l) {
  __builtin_amdgcn_global_load_lds(
      (const __attribute__((address_space(1))) unsigned int*)g,
      (__attribute__((address_space(3))) unsigned int*)l, 16, 0, 0);
}

// ---------------------------------------------------------------------------
// act2: fused upsample(x2,edge) -> snake_beta -> downsample(/2,edge).
// Register-resident: thread = (channel c, 16 consecutive t). Identity:
// sb[2tb-5+j], j=2m and 2m+1 both read x window xv[m..m+5]:
//   sbv[2m]   (p odd,  q=tb-3+m): 2*sum_s F[2s+1]*xv[m+s]
//   sbv[2m+1] (p even, q=tb-2+m): 2*sum_s F[2s]  *xv[m+s]
// then snake; down: acc[i] = sum_u F[u]*sbv[2i+u].
// Edge blocks (p clamp active) take the generic wave-uniform path.
// TOUT=true : out bf16 transposed [B][T][C] (conv B-operand layout)
// TOUT=false: out fp32 [B][C][T] + residual (final stage)
// ---------------------------------------------------------------------------
template <typename TIN, bool TOUT>
__global__ __launch_bounds__(256) void act2(
    const TIN* __restrict__ in, void* __restrict__ out_,
    const float* __restrict__ alpha_log, const float* __restrict__ beta_log,
    const float* __restrict__ resid, int C, int T, Filt fl)
{
  __shared__ float xs[64 * 75];  // row stride 75 (odd -> conflict-free), 74 used
  const int t0 = blockIdx.x * 64;
  const int c0 = blockIdx.y * 64;
  const int b  = blockIdx.z;
  const int tid = threadIdx.x;

  // Stage x rows: xs[c][j] = x[clamp(t0-5+j)], j<74 (coalesced along t)
  for (int i = tid; i < 64 * 74; i += 256) {
    int c = i / 74, j = i - c * 74;
    int t = min(max(t0 - 5 + j, 0), T - 1);
    xs[c * 75 + j] = (float)in[((long)(b * C + c0 + c)) * T + t];
  }
  __syncthreads();

  const int c  = tid & 63;
  const int tg = tid >> 6;
  const int tb = t0 + tg * 16;
  const float a  = __expf(alpha_log[c0 + c]);
  const float rb = 1.0f / (__expf(beta_log[c0 + c]) + 1e-9f);

  float sbv[42];
  const bool interior = (2 * tb - 5 >= 0) && (2 * tb + 36 <= 2 * T - 1);  // wave-uniform
  if (interior) {
    float xv[26];
    const float* xr = xs + c * 75 + tg * 16;  // xv[m] = x[tb-5+m]
#pragma unroll
    for (int m = 0; m < 26; ++m) xv[m] = xr[m];
#pragma unroll
    for (int m = 0; m <= 20; ++m) {
      float uo = fl.f[1] * xv[m]     + fl.f[3] * xv[m + 1] + fl.f[5]  * xv[m + 2]
               + fl.f[7] * xv[m + 3] + fl.f[9] * xv[m + 4] + fl.f[11] * xv[m + 5];
      float ue = fl.f[0] * xv[m]     + fl.f[2] * xv[m + 1] + fl.f[4]  * xv[m + 2]
               + fl.f[6] * xv[m + 3] + fl.f[8] * xv[m + 4] + fl.f[10] * xv[m + 5];
      uo *= 2.0f; ue *= 2.0f;
      float s0 = __sinf(a * uo);
      float s1 = __sinf(a * ue);
      sbv[2 * m]     = uo + rb * s0 * s0;
      sbv[2 * m + 1] = ue + rb * s1 * s1;
    }
  } else {
    const float* xr = xs + c * 75;  // xr[idx] = x[clamp(t0-5+idx)]
#pragma unroll
    for (int j = 0; j < 42; ++j) {
      int p = 2 * tb - 5 + j;
      int pc = min(max(p, 0), 2 * T - 1);
      float up;
      if (pc & 1) {
        int q = (pc - 1) >> 1;
        int base = q - t0 + 3;  // x[q-2]
        up = fl.f[1] * xr[base]     + fl.f[3] * xr[base + 1] + fl.f[5]  * xr[base + 2]
           + fl.f[7] * xr[base + 3] + fl.f[9] * xr[base + 4] + fl.f[11] * xr[base + 5];
      } else {
        int q = pc >> 1;
        int base = q - t0 + 2;  // x[q-3]
        up = fl.f[0] * xr[base]     + fl.f[2] * xr[base + 1] + fl.f[4]  * xr[base + 2]
           + fl.f[6] * xr[base + 3] + fl.f[8] * xr[base + 4] + fl.f[10] * xr[base + 5];
      }
      up *= 2.0f;
      float s = __sinf(a * up);
      sbv[j] = up + rb * s * s;
    }
  }

  float acc[16];
#pragma unroll
  for (int i = 0; i < 16; ++i) {
    float s = 0.0f;
#pragma unroll
    for (int u = 0; u < 12; ++u) s += fl.f[u] * sbv[2 * i + u];
    acc[i] = s;
  }

  if constexpr (TOUT) {
    __hip_bfloat16* out = (__hip_bfloat16*)out_;
#pragma unroll
    for (int i = 0; i < 16; ++i)  // lanes = 64 consecutive c -> 128B/instr
      out[((long)b * T + tb + i) * C + c0 + c] = __float2bfloat16(acc[i]);
  } else {
    float* out = (float*)out_;
    __syncthreads();            // all xs reads done before reuse
    float* ys = xs;             // ys[c][tl], stride 65 (odd)
#pragma unroll
    for (int i = 0; i < 16; ++i) ys[c * 65 + tg * 16 + i] = acc[i];
    __syncthreads();
    for (int i = tid; i < 64 * 64; i += 256) {
      int cc = i >> 6, tl = i & 63;
      long o = ((long)(b * C + c0 + cc)) * T + t0 + tl;
      out[o] = ys[cc * 65 + tl] + resid[o];
    }
  }
}

// ---------------------------------------------------------------------------
// Weight pre-conversion: w fp32 [co][ci][3] -> bf16 [d][co][ci]
// ---------------------------------------------------------------------------
__global__ __launch_bounds__(256) void wconv(
    const float* __restrict__ w, ushort* __restrict__ wbf, int C)
{
  int idx = blockIdx.x * 256 + threadIdx.x;
  int total = 3 * C * C;
  if (idx >= total) return;
  int d = idx / (C * C);
  int r = idx - d * C * C;          // co*C + ci
  wbf[idx] = f2bf(w[(long)r * 3 + d]);
}

// ---------------------------------------------------------------------------
// conv_mfma: out[b,co,t] = bias[co] + sum_{ci,d} w[co,ci,d]*in[b,ci,t-1+d]
// (zero pad). Implicit GEMM via mfma_f32_16x16x32_bf16, tap-decomposed.
// Staging now pure 16B global_load_lds (full waves, wave-uniform LDS base);
// halo rows (t0-1, t0+NTC) via 8 bounds-checked ds_writes.
// ---------------------------------------------------------------------------
#define MT 64
#define NTC 256
#define BK 32

__global__ __launch_bounds__(256) void conv_mfma(
    const __hip_bfloat16* __restrict__ inT,  // [B][T][C] bf16
    const ushort* __restrict__ wbf,          // [3][C(co)][C(ci)] bf16
    const float* __restrict__ bias,
    __hip_bfloat16* __restrict__ out,        // [B][C][T] bf16
    int C, int T)
{
  __shared__ ushort wl[3][MT][BK];           // slot g=((d*64+co)*4+seg) at byte g*16
  __shared__ ushort xs[NTC + 2][BK];         // slot g=(tl*4+seg) at byte g*16
  const int t0  = blockIdx.x * NTC;
  const int co0 = blockIdx.y * MT;
  const int b   = blockIdx.z;
  const int tid  = threadIdx.x;
  const int lane = tid & 63;
  const int wave = tid >> 6;
  const int ln15 = lane & 15;
  const int quad = lane >> 4;
  const ushort* inU = (const ushort*)inT;

  f32x4 acc[4][4];
#pragma unroll
  for (int mi = 0; mi < 4; ++mi)
#pragma unroll
    for (int ni = 0; ni < 4; ++ni) acc[mi][ni] = (f32x4){0.f, 0.f, 0.f, 0.f};

  ushort* wlf = &wl[0][0][0];
  ushort* xsf = &xs[0][0];

  for (int ci0 = 0; ci0 < C; ci0 += BK) {
    __syncthreads();
    // --- weights: 768 slots of 16B, 3 full-wave iterations
#pragma unroll
    for (int it = 0; it < 3; ++it) {
      int g = it * 256 + tid;
      int d = g >> 8, co = (g >> 2) & 63, seg = g & 3;
      const ushort* gsrc = wbf + ((long)d * C + co0 + co) * C + ci0 + seg * 8;
      gl_lds16(gsrc, wlf + (size_t)(it * 256 + (tid & ~63)) * 8);
    }
    // --- input interior rows tl=1..256 (t always in-bounds): slots 4..1027
#pragma unroll
    for (int it = 0; it < 4; ++it) {
      int g = it * 256 + tid + 4;
      int tl = g >> 2, seg = g & 3;
      int t = t0 - 1 + tl;
      const ushort* gsrc = inU + ((long)b * T + t) * C + ci0 + seg * 8;
      gl_lds16(gsrc, xsf + (size_t)(it * 256 + (tid & ~63) + 4) * 8);
    }
    // --- halo rows tl=0 (t0-1) and tl=257 (t0+NTC), zero-padded
    if (tid < 8) {
      int g = (tid < 4) ? tid : (1028 + tid - 4);
      int tl = g >> 2, seg = g & 3;
      int t = t0 - 1 + tl;
      uint4 v = {0u, 0u, 0u, 0u};
      if (t >= 0 && t < T)
        v = *(const uint4*)(inU + ((long)b * T + t) * C + ci0 + seg * 8);
      *(uint4*)&xs[tl][seg * 8] = v;
    }
    __syncthreads();

#pragma unroll
    for (int d = 0; d < 3; ++d) {
      bf16x8 afr[4], bfr[4];
#pragma unroll
      for (int mi = 0; mi < 4; ++mi)
        afr[mi] = *(const bf16x8*)&wl[d][mi * 16 + ln15][quad * 8];
#pragma unroll
      for (int ni = 0; ni < 4; ++ni)
        bfr[ni] = *(const bf16x8*)&xs[wave * 64 + ni * 16 + ln15 + d][quad * 8];
#pragma unroll
      for (int mi = 0; mi < 4; ++mi)
#pragma unroll
        for (int ni = 0; ni < 4; ++ni)
          acc[mi][ni] = __builtin_amdgcn_mfma_f32_16x16x32_bf16(
              afr[mi], bfr[ni], acc[mi][ni], 0, 0, 0);
    }
  }

  // epilogue: D[m][n]: n(t)=lane&15, m(co)=quad*4+reg
#pragma unroll
  for (int mi = 0; mi < 4; ++mi) {
#pragma unroll
    for (int r = 0; r < 4; ++r) {
      int co = co0 + mi * 16 + quad * 4 + r;
      float bv = bias[co];
      long orow = ((long)(b * C + co)) * T;
#pragma unroll
      for (int ni = 0; ni < 4; ++ni) {
        int t = t0 + wave * 64 + ni * 16 + ln15;
        out[orow + t] = __float2bfloat16(acc[mi][ni][r] + bv);
      }
    }
  }
}

// ---------------------------------------------------------------------------
// Pipeline. Weight bf16 scratch lives in d_out's head (3MB), fully
// overwritten by the final act2 which writes all B*C*T floats.
// ws = 2 x 67MB bf16 ping-pong.
// ---------------------------------------------------------------------------
extern "C" void kernel_launch(void* const* d_in, const int* in_sizes, int n_in,
                              void* d_out, int out_size, void* d_ws, size_t ws_size,
                              hipStream_t stream) {
  const float* x      = (const float*)d_in[0];
  const float* w1     = (const float*)d_in[1];
  const float* b1     = (const float*)d_in[2];
  const float* w2     = (const float*)d_in[3];
  const float* b2     = (const float*)d_in[4];
  const float* alpha1 = (const float*)d_in[5];
  const float* beta1  = (const float*)d_in[6];
  const float* alpha2 = (const float*)d_in[7];
  const float* beta2  = (const float*)d_in[8];
  float* out = (float*)d_out;

  const int C = in_sizes[2];             // 512
  const long total = (long)in_sizes[0];  // B*C*T
  const int T = 8192;
  const int B = (int)(total / ((long)C * T));

  __hip_bfloat16* ws0 = (__hip_bfloat16*)d_ws;        // [B][T][C]
  __hip_bfloat16* ws1 = ws0 + (size_t)B * C * T;      // [B][C][T]
  ushort* w1bf = (ushort*)d_out;                      // scratch in out head
  ushort* w2bf = w1bf + (size_t)3 * C * C;

  Filt fl;
  compute_filter(fl.f);

  dim3 actGrid(T / 64, C / 64, B);
  dim3 convGrid(T / NTC, C / MT, B);
  int wblocks = (3 * C * C + 255) / 256;

  wconv<<<wblocks, 256, 0, stream>>>(w1, w1bf, C);
  wconv<<<wblocks, 256, 0, stream>>>(w2, w2bf, C);
  act2<float, true><<<actGrid, 256, 0, stream>>>(x, ws0, alpha1, beta1, nullptr, C, T, fl);
  conv_mfma<<<convGrid, 256, 0, stream>>>(ws0, w1bf, b1, ws1, C, T);
  act2<__hip_bfloat16, true><<<actGrid, 256, 0, stream>>>(ws1, ws0, alpha1, beta1, nullptr, C, T, fl);
  conv_mfma<<<convGrid, 256, 0, stream>>>(ws0, w2bf, b2, ws1, C, T);
  act2<__hip_bfloat16, false><<<actGrid, 256, 0, stream>>>(ws1, out, alpha2, beta2, x, C, T, fl);
}